// Round 22
// baseline (102.424 us; speedup 1.0000x reference)
//
#include <hip/hip_runtime.h>
#include <hip/hip_bf16.h>
#include <cstdint>
#include <cstddef>

// Problem constants
#define BDIM   32768
#define KDIM   2048
#define NDIM   128
#define VHEADS 20
#define PDIM   6
#define RLORA  10

#define BK      32
#define NCHUNK  (KDIM / BK)                 // 64
#define OUT_ELEMS   (BDIM * VHEADS * PDIM)  // 3932160
#define WS_W_BYTES  (KDIM * NDIM * 2)       // 524288

typedef __attribute__((ext_vector_type(8))) __bf16 bf16x8;
typedef __attribute__((ext_vector_type(4))) float f32x4;
typedef __attribute__((ext_vector_type(2))) float f32x2;
typedef __attribute__((ext_vector_type(4))) unsigned int u32x4;

union FragU { bf16x8 b; u32x4 u; };

__device__ __forceinline__ unsigned int cvt_pk_bf16(float lo, float hi) {
  unsigned int r;
  asm("v_cvt_pk_bf16_f32 %0, %1, %2" : "=v"(r) : "v"(lo), "v"(hi));
  return r;
}

__device__ __forceinline__ void gload_lds16(const void* g, void* l) {
  __builtin_amdgcn_global_load_lds(
      (const __attribute__((address_space(1))) void*)(g),
      (__attribute__((address_space(3))) void*)(l), 16, 0, 0);
}

__device__ __forceinline__ float fast_tanh(float x) {
  float ax = fabsf(x);
  float e  = __expf(-2.0f * ax);
  float t  = __fdividef(1.0f - e, 1.0f + e);
  return copysignf(t, x);
}

#define SBAR() __builtin_amdgcn_sched_barrier(0)

// ---------------------------------------------------------------------------
// k0: pack We1 f32[2048][128] -> bf16, PER-K32-CHUNK-CONTIGUOUS fragments
// (R12 layout): byte offset ((c*8 + nt)*64 + lane)*16 holds the 8 bf16 for
//   n = nt*16 + (lane&15), k = c*32 + (lane>>4)*8 + j  (j = 0..7).
// Chunk c = 8 KB at c*8192; fragment nt at nt*1024 + lane*16.
// Also M = lora_A @ lora_B ([2][120]).
// ---------------------------------------------------------------------------
__global__ __launch_bounds__(256)
void k0_pack(const float* __restrict__ We1,
             const float* __restrict__ lA,
             const float* __restrict__ lB,
             unsigned short* __restrict__ wsw,
             float* __restrict__ wsM) {
  if (blockIdx.x == 128) {
    int t = threadIdx.x;
    if (t < 2 * VHEADS * PDIM) {
      int d  = t / (VHEADS * PDIM);
      int vp = t - d * (VHEADS * PDIM);
      float s = 0.f;
#pragma unroll
      for (int r = 0; r < RLORA; ++r)
        s = fmaf(lA[d * RLORA + r], lB[r * (VHEADS * PDIM) + vp], s);
      wsM[t] = s;  // layout [d][vp]
    }
    return;
  }
  int t    = blockIdx.x * 256 + threadIdx.x;  // 0..32767
  int lane = t & 63;
  int g    = t >> 6;        // 0..511
  int nt   = g & 7;
  int c    = g >> 3;        // 0..63
  int n    = nt * 16 + (lane & 15);
  int kb   = c * BK + (lane >> 4) * 8;

  unsigned int u[4];
#pragma unroll
  for (int q = 0; q < 4; ++q) {
    float f0 = We1[(size_t)(kb + 2 * q + 0) * NDIM + n];
    float f1 = We1[(size_t)(kb + 2 * q + 1) * NDIM + n];
    __hip_bfloat16 h0 = __float2bfloat16(f0);
    __hip_bfloat16 h1 = __float2bfloat16(f1);
    u[q] = (unsigned int)*reinterpret_cast<unsigned short*>(&h0) |
           ((unsigned int)*reinterpret_cast<unsigned short*>(&h1) << 16);
  }
  *reinterpret_cast<u32x4*>(wsw + (size_t)t * 8) = u32x4{u[0], u[1], u[2], u[3]};
}

// ---------------------------------------------------------------------------
// k1: fused encoder + heads.  R14's VERIFIED cadence at BK=32 -> 4 blocks/CU.
//   512 blocks x 512 thr (8 waves: wr = wv&3 row-group x16, wc = wv>>2
//   col-half x64).  Parameter-only change from R14 (sync structure
//   untouched): BK 64->32 halves LDS to ~34 KB (A dbuf 2x8 KB + B dbuf
//   2x8 KB, four STATIC arrays) -> 4 blocks/CU = 32 waves/CU.  Four
//   independent block-convoys per CU fill each other's vmcnt/barrier stalls.
//   Per chunk: 1 A-DMA + 1 B-DMA per thread; uniform s_waitcnt vmcnt(2)
//   (next chunk's 2 loads stay in flight across BOTH raw s_barriers --
//   never drained to 0 in the loop); unroll-2 so all buffers are
//   compile-time-distinct.
//   A: f32 [64][32] (8 KB) via global_load_lds, linear dest, source granule
//      pre-XOR-swizzled g^(row&7) within the 8-granule row.
//   B: per-K32-chunk 8 KB fragment pack, linear dest.
//   Epilogue: be1/relu/We2 partials, shfl-reduce, cross-half combine -> z;
//   fused heads (8 wave-slots; row = lane).
// ---------------------------------------------------------------------------
__global__ __launch_bounds__(512, 4)
void k1_fused(const float* __restrict__ x,
              const unsigned short* __restrict__ wp,
              const float* __restrict__ be1,
              const float* __restrict__ We2,
              const float* __restrict__ be2,
              const float* __restrict__ W1,
              const float* __restrict__ b1,
              const float* __restrict__ W2,
              const float* __restrict__ b2,
              const float* __restrict__ M,
              float* __restrict__ out,
              float* __restrict__ zout) {
  __shared__ char A0_[8192] __attribute__((aligned(16)));
  __shared__ char A1_[8192] __attribute__((aligned(16)));
  __shared__ char B0_[8192] __attribute__((aligned(16)));
  __shared__ char B1_[8192] __attribute__((aligned(16)));
  __shared__ float zpart2[64][2][2];   // [row][col-half][d]
  __shared__ float zsh[64][2];

  const int tid  = threadIdx.x;        // 0..511
  const int lane = tid & 63;
  const int wv   = tid >> 6;           // 0..7
  const int wr   = wv & 3;             // row-group (x16)
  const int wc   = wv >> 2;            // col-half (x64)
  const int l15  = lane & 15;
  const int kgrp = lane >> 4;          // 0..3
  const int blk  = blockIdx.x;

  f32x4 acc[4];
#pragma unroll
  for (int i = 0; i < 4; ++i) acc[i] = f32x4{0.f, 0.f, 0.f, 0.f};

  // A staging geometry: slot s = tid (512 x 16 B = 8 KB): row = s>>3
  // (0..63), dest granule s&7, source granule (s&7)^(row&7).
  const int arow = tid >> 3;
  const int agr  = (tid & 7) ^ (arow & 7);
  const float* abase_g = x + (size_t)(blk * 64 + arow) * KDIM + agr * 4;

  auto STAGE = [&](char* Ad, char* Bd, int c) {
    gload_lds16(abase_g + c * BK, Ad + tid * 16);
    gload_lds16((const char*)wp + (size_t)c * 8192 + tid * 16, Bd + tid * 16);
  };

  auto COMPUTE = [&](const char* Ad, const char* Bd) {
    const int row = wr * 16 + l15;
    const char* ab = Ad + row * 128;
    const int rx = row & 7;
    f32x4 lo = *(const f32x4*)(ab + (((kgrp * 2 + 0) ^ rx) << 4));
    f32x4 hi = *(const f32x4*)(ab + (((kgrp * 2 + 1) ^ rx) << 4));
    FragU a;
    a.u = u32x4{cvt_pk_bf16(lo.x, lo.y), cvt_pk_bf16(lo.z, lo.w),
                cvt_pk_bf16(hi.x, hi.y), cvt_pk_bf16(hi.z, hi.w)};
    const char* bbase = Bd + lane * 16;
#pragma unroll
    for (int nt = 0; nt < 4; ++nt) {
      FragU b;
      b.u = *(const u32x4*)(bbase + (wc * 4 + nt) * 1024);
      acc[nt] = __builtin_amdgcn_mfma_f32_16x16x32_bf16(a.b, b.b, acc[nt], 0, 0, 0);
    }
  };

  // prologue: chunks 0,1 in flight (4 loads/thread)
  STAGE(A0_, B0_, 0);
  STAGE(A1_, B1_, 1);

#pragma unroll 1
  for (int cc = 0; cc < NCHUNK / 2 - 1; ++cc) {   // computes 2cc, 2cc+1
    asm volatile("s_waitcnt vmcnt(2)" ::: "memory");   // chunk 2cc landed
    SBAR();
    __builtin_amdgcn_s_barrier();
    COMPUTE(A0_, B0_);
    __builtin_amdgcn_s_barrier();
    SBAR();
    STAGE(A0_, B0_, 2 * cc + 2);                       // back to 4 in flight
    asm volatile("s_waitcnt vmcnt(2)" ::: "memory");   // chunk 2cc+1 landed
    SBAR();
    __builtin_amdgcn_s_barrier();
    COMPUTE(A1_, B1_);
    __builtin_amdgcn_s_barrier();
    SBAR();
    STAGE(A1_, B1_, 2 * cc + 3);
  }
  // tail: chunks 62, 63 (no further staging)
  asm volatile("s_waitcnt vmcnt(2)" ::: "memory");
  SBAR();
  __builtin_amdgcn_s_barrier();
  COMPUTE(A0_, B0_);
  asm volatile("s_waitcnt vmcnt(0)" ::: "memory");
  SBAR();
  __builtin_amdgcn_s_barrier();
  COMPUTE(A1_, B1_);

  // ---- epilogue: +be1, relu, @We2 partials (this wave's 64 cols)
  float part[4][2];
#pragma unroll
  for (int j = 0; j < 4; ++j) { part[j][0] = 0.f; part[j][1] = 0.f; }
#pragma unroll
  for (int nt = 0; nt < 4; ++nt) {
    int col = (wc * 4 + nt) * 16 + l15;
    float bb = be1[col];
    float w0 = We2[col * 2 + 0];
    float w1 = We2[col * 2 + 1];
#pragma unroll
    for (int j = 0; j < 4; ++j) {
      float h = acc[nt][j] + bb;
      h = h > 0.f ? h : 0.f;
      part[j][0] = fmaf(h, w0, part[j][0]);
      part[j][1] = fmaf(h, w1, part[j][1]);
    }
  }
#pragma unroll
  for (int m = 1; m < 16; m <<= 1) {
#pragma unroll
    for (int j = 0; j < 4; ++j) {
      part[j][0] += __shfl_xor(part[j][0], m, 64);
      part[j][1] += __shfl_xor(part[j][1], m, 64);
    }
  }
  if (l15 == 0) {
#pragma unroll
    for (int j = 0; j < 4; ++j) {
      int rl = wr * 16 + kgrp * 4 + j;   // C row = (lane>>4)*4 + reg
      zpart2[rl][wc][0] = part[j][0];
      zpart2[rl][wc][1] = part[j][1];
    }
  }
  __syncthreads();
  if (tid < 64) {
    float s0 = zpart2[tid][0][0] + zpart2[tid][1][0] + be2[0];
    float s1 = zpart2[tid][0][1] + zpart2[tid][1][1] + be2[1];
    zsh[tid][0] = s0;
    zsh[tid][1] = s1;
    f32x2 zz = {s0, s1};
    *(f32x2*)(zout + (size_t)(blk * 64 + tid) * 2) = zz;
  }
  __syncthreads();

  // ---- heads: row = lane, head slots per wave: wv, wv+8, (wv<4: wv+16)
  const int wvu = __builtin_amdgcn_readfirstlane(wv);
  float z0 = zsh[lane][0];
  float z1 = zsh[lane][1];
  float* orow = out + (size_t)(blk * 64 + lane) * (VHEADS * PDIM);

  auto head = [&](int v) {
    const float* w1a = W1 + (size_t)(v * 2 + 0) * NDIM;
    const float* w1b = W1 + (size_t)(v * 2 + 1) * NDIM;
    const float* bb1 = b1 + (size_t)v * NDIM;
    const float* w2  = W2 + (size_t)v * NDIM * PDIM;

    float p[6] = {0.f, 0.f, 0.f, 0.f, 0.f, 0.f};
#pragma unroll 4
    for (int h = 0; h < NDIM; ++h) {
      float hv = fmaf(z0, w1a[h], fmaf(z1, w1b[h], bb1[h]));
      hv = hv > 0.f ? hv : 0.f;
#pragma unroll
      for (int j = 0; j < 6; ++j) p[j] = fmaf(hv, w2[h * 6 + j], p[j]);
    }
    float o[6];
#pragma unroll
    for (int j = 0; j < 6; ++j) {
      float t1 = fast_tanh(p[j] + b2[v * PDIM + j]);
      float lo = fmaf(z0, M[v * PDIM + j], z1 * M[VHEADS * PDIM + v * PDIM + j]);
      o[j] = fast_tanh(fmaf(0.15f, lo, t1));
    }
    float* op = orow + v * PDIM;
    f32x2 o01 = {o[0], o[1]};
    f32x2 o23 = {o[2], o[3]};
    f32x2 o45 = {o[4], o[5]};
    __builtin_nontemporal_store(o01, (f32x2*)(op + 0));
    __builtin_nontemporal_store(o23, (f32x2*)(op + 2));
    __builtin_nontemporal_store(o45, (f32x2*)(op + 4));
  };

  head(wvu);
  head(wvu + 8);
  if (wvu < 4) head(wvu + 16);
}

// ---------------------------------------------------------------------------
extern "C" void kernel_launch(void* const* d_in, const int* in_sizes, int n_in,
                              void* d_out, int out_size, void* d_ws, size_t ws_size,
                              hipStream_t stream) {
  const float* x   = (const float*)d_in[0];
  const float* We1 = (const float*)d_in[1];
  const float* be1 = (const float*)d_in[2];
  const float* We2 = (const float*)d_in[3];
  const float* be2 = (const float*)d_in[4];
  const float* W1  = (const float*)d_in[5];
  const float* b1  = (const float*)d_in[6];
  const float* W2  = (const float*)d_in[7];
  const float* b2  = (const float*)d_in[8];
  const float* lA  = (const float*)d_in[9];
  const float* lB  = (const float*)d_in[10];

  float* out  = (float*)d_out;
  float* zout = out + OUT_ELEMS;                       // second tuple output
  unsigned short* wsw = (unsigned short*)d_ws;         // 512 KB bf16 W pack
  float* wsM = (float*)((char*)d_ws + WS_W_BYTES);     // 240 floats

  hipLaunchKernelGGL(k0_pack, dim3(129), dim3(256), 0, stream,
                     We1, lA, lB, wsw, wsM);
  hipLaunchKernelGGL(k1_fused, dim3(BDIM / 64), dim3(512), 0, stream,
                     x, wsw, be1, We2, be2, W1, b1, W2, b2, wsM, out, zout);
}